// Round 5
// baseline (108.823 us; speedup 1.0000x reference)
//
#include <hip/hip_runtime.h>
#include <hip/hip_bf16.h>

typedef __attribute__((ext_vector_type(8))) short bf16x8;
typedef __attribute__((ext_vector_type(4))) float f32x4;

#define D_DIM 256   // input feature dim
#define H_DIM 128   // hidden dim per branch
#define MAX_RS 25088  // max rows per LDS half-range (100352 B LDS)

// RNE float->bf16 (bit pattern)
__device__ inline ushort f2bf(float f) {
    union { float f; unsigned u; } a; a.f = f;
    unsigned r = a.u + 0x7fffu + ((a.u >> 16) & 1u);
    return (ushort)(r >> 16);
}

// K0: build Wt bf16 [hcat][k]; optionally init rowsum(=dis buf) for fallback path.
__global__ void k0_init(const float* __restrict__ W_nb, const float* __restrict__ W_self,
                        ushort* __restrict__ Wt, float* __restrict__ dis, int N, int init_dis) {
    int i = blockIdx.x * 256 + threadIdx.x;
    if (i < 2 * H_DIM * D_DIM) {
        int sel = i >> 15;
        int r   = i & 32767;
        int k   = r >> 7;
        int h   = r & 127;
        const float* W = sel ? W_self : W_nb;
        Wt[(sel * H_DIM + h) * D_DIM + k] = f2bf(W[k * H_DIM + h]);
    }
    if (init_dis && i < N) dis[i] = 1e-10f;
}

// K1: per-node fused GEMM (unchanged from R3): g_nb[n], g_self[n].
__global__ __launch_bounds__(128, 2) void k1_gemm(
    const float* __restrict__ x, const ushort* __restrict__ Wt,
    const float* __restrict__ b_nb, const float* __restrict__ b_self,
    const float* __restrict__ W_att,
    float* __restrict__ g_nb, float* __restrict__ g_self, int N)
{
    __shared__ __align__(16) ushort A_lds[64][72];
    __shared__ __align__(16) ushort B_lds[256][72];

    const int t    = threadIdx.x;
    const int lane = t & 63;
    const int wave = t >> 6;
    const int li   = lane & 15;
    const int grp  = lane >> 4;
    const int block_row = blockIdx.x * 64;

    f32x4 acc[2][16];
    #pragma unroll
    for (int mi = 0; mi < 2; mi++)
        #pragma unroll
        for (int ni = 0; ni < 16; ni++) acc[mi][ni] = f32x4{0.f, 0.f, 0.f, 0.f};

    const int arow  = t >> 1;
    const int ahalf = t & 1;
    const int garow = block_row + arow;
    const bool avalid = garow < N;

    for (int kt = 0; kt < 4; kt++) {
        const int k0 = kt * 64;
        __syncthreads();
        {
            ushort4 o[8];
            if (avalid) {
                const float4* src = reinterpret_cast<const float4*>(x + (size_t)garow * D_DIM + k0 + ahalf * 32);
                #pragma unroll
                for (int j = 0; j < 8; j++) {
                    float4 v = src[j];
                    o[j].x = f2bf(v.x); o[j].y = f2bf(v.y); o[j].z = f2bf(v.z); o[j].w = f2bf(v.w);
                }
            } else {
                #pragma unroll
                for (int j = 0; j < 8; j++) { o[j].x = 0; o[j].y = 0; o[j].z = 0; o[j].w = 0; }
            }
            #pragma unroll
            for (int j = 0; j < 8; j++)
                *reinterpret_cast<ushort4*>(&A_lds[arow][ahalf * 32 + j * 4]) = o[j];
        }
        #pragma unroll
        for (int rr = 0; rr < 2; rr++) {
            int hrow = t + rr * 128;
            const uint4* src = reinterpret_cast<const uint4*>(Wt + hrow * D_DIM + k0);
            uint4* dst = reinterpret_cast<uint4*>(&B_lds[hrow][0]);
            #pragma unroll
            for (int j = 0; j < 8; j++) dst[j] = src[j];
        }
        __syncthreads();

        bf16x8 afrag[2][2];
        #pragma unroll
        for (int mi = 0; mi < 2; mi++)
            #pragma unroll
            for (int kk = 0; kk < 2; kk++)
                afrag[mi][kk] = *reinterpret_cast<const bf16x8*>(
                    &A_lds[wave * 32 + mi * 16 + li][kk * 32 + grp * 8]);
        #pragma unroll
        for (int ni = 0; ni < 16; ni++) {
            bf16x8 b0 = *reinterpret_cast<const bf16x8*>(&B_lds[ni * 16 + li][grp * 8]);
            bf16x8 b1 = *reinterpret_cast<const bf16x8*>(&B_lds[ni * 16 + li][32 + grp * 8]);
            #pragma unroll
            for (int mi = 0; mi < 2; mi++) {
                acc[mi][ni] = __builtin_amdgcn_mfma_f32_16x16x32_bf16(afrag[mi][0], b0, acc[mi][ni], 0, 0, 0);
                acc[mi][ni] = __builtin_amdgcn_mfma_f32_16x16x32_bf16(afrag[mi][1], b1, acc[mi][ni], 0, 0, 0);
            }
        }
    }

    float pn[2][4], ps[2][4];
    #pragma unroll
    for (int mi = 0; mi < 2; mi++)
        #pragma unroll
        for (int r = 0; r < 4; r++) { pn[mi][r] = 0.f; ps[mi][r] = 0.f; }

    #pragma unroll
    for (int ni = 0; ni < 16; ni++) {
        int hcat = ni * 16 + li;
        int hh   = hcat & 127;
        float bias = (ni < 8) ? b_nb[hh] : b_self[hh];
        float aw   = W_att[hcat];
        #pragma unroll
        for (int mi = 0; mi < 2; mi++)
            #pragma unroll
            for (int r = 0; r < 4; r++) {
                float y = acc[mi][ni][r] + bias;
                y = y > 0.f ? y : 0.f;
                if (ni < 8) pn[mi][r] += y * aw; else ps[mi][r] += y * aw;
            }
    }

    #pragma unroll
    for (int mi = 0; mi < 2; mi++)
        #pragma unroll
        for (int r = 0; r < 4; r++) {
            float a_ = pn[mi][r], s_ = ps[mi][r];
            #pragma unroll
            for (int m = 1; m < 16; m <<= 1) {
                a_ += __shfl_xor(a_, m);
                s_ += __shfl_xor(s_, m);
            }
            if (li == 0) {
                int n = block_row + wave * 32 + mi * 16 + grp * 4 + r;
                if (n < N) { g_nb[n] = a_; g_self[n] = s_; }
            }
        }
}

// K2a: gate/mask only -> mv in d_out. NO atomics. 4 edges/thread vectorized.
__global__ __launch_bounds__(256) void k2a_gate(
    const int* __restrict__ row, const int* __restrict__ col,
    const float* __restrict__ values, const float* __restrict__ noise,
    const float* __restrict__ g_nb, const float* __restrict__ g_self,
    const float* __restrict__ b_att, float* __restrict__ mv_out, int E)
{
    int i = (blockIdx.x * 256 + threadIdx.x) * 4;
    if (i >= E) return;
    float ba = b_att[0];
    if (i + 3 < E) {
        int4   r4 = *reinterpret_cast<const int4*>(row + i);
        int4   c4 = *reinterpret_cast<const int4*>(col + i);
        float4 v4 = *reinterpret_cast<const float4*>(values + i);
        float4 u4 = *reinterpret_cast<const float4*>(noise + i);
        int   rr[4] = { r4.x, r4.y, r4.z, r4.w };
        int   cc[4] = { c4.x, c4.y, c4.z, c4.w };
        float vv[4] = { v4.x, v4.y, v4.z, v4.w };
        float uu[4] = { u4.x, u4.y, u4.z, u4.w };
        float mv[4];
        #pragma unroll
        for (int j = 0; j < 4; j++) {
            float la   = g_nb[rr[j]] + g_self[cc[j]] + ba;
            float u    = uu[j] + 1e-7f;
            float gate = u / (u + (1.f - u) * __expf(-la));
            float mask = fminf(fmaxf(gate * 1.6f - 0.5f, 0.f), 1.f);
            mv[j] = vv[j] * mask;
        }
        *reinterpret_cast<float4*>(mv_out + i) = make_float4(mv[0], mv[1], mv[2], mv[3]);
    } else {
        for (int j = 0; j < 4 && i + j < E; j++) {
            int e = i + j;
            float la   = g_nb[row[e]] + g_self[col[e]] + ba;
            float u    = noise[e] + 1e-7f;
            float gate = u / (u + (1.f - u) * __expf(-la));
            float mask = fminf(fmaxf(gate * 1.6f - 0.5f, 0.f), 1.f);
            mv_out[e] = values[e] * mask;
        }
    }
}

// K2b: LDS-privatized scatter. Block (s,g): edge slice s, row half-range g.
// Accumulate in 100KB LDS via ds_add_f32, flush coalesced to priv[s].
__global__ __launch_bounds__(512, 1) void k2b_scatter(
    const int* __restrict__ row, const float* __restrict__ mv,
    float* __restrict__ priv, int E, int ES, int RS, int Npad)
{
    __shared__ float acc[MAX_RS];
    const int s = blockIdx.x >> 1;
    const int g = blockIdx.x & 1;
    const int t = threadIdx.x;

    for (int i = t; i < RS; i += 512) acc[i] = 0.f;
    __syncthreads();

    const int base = s * ES;
    int cnt = E - base; if (cnt > ES) cnt = ES;
    const int lo = g * RS;
    for (int i = t; i < cnt; i += 512) {
        int   r = row[base + i];
        int   d = r - lo;
        if ((unsigned)d < (unsigned)RS)
            atomicAdd(&acc[d], mv[base + i]);
    }
    __syncthreads();

    float* dst = priv + (size_t)s * Npad + lo;
    for (int i = t; i < RS; i += 512) dst[i] = acc[i];
}

// K2c: fold partials -> dis[n] = rsqrt(1e-10 + sum_s priv[s][n])
__global__ __launch_bounds__(256) void k2c_reduce(
    const float* __restrict__ priv, float* __restrict__ dis, int N, int Npad, int S)
{
    int n = blockIdx.x * 256 + threadIdx.x;
    if (n >= N) return;
    float sum = 1e-10f;
    for (int s = 0; s < S; s++) sum += priv[(size_t)s * Npad + n];
    dis[n] = rsqrtf(sum);
}

// Fallback (small ws): global atomics into dis-as-rowsum.
__global__ __launch_bounds__(256) void k2b_atomic_fb(
    const int* __restrict__ row, const float* __restrict__ mv,
    float* __restrict__ rowsum, int E)
{
    int e = blockIdx.x * 256 + threadIdx.x;
    if (e >= E) return;
    atomicAdd(&rowsum[row[e]], mv[e]);
}
__global__ __launch_bounds__(256) void k2c_rsqrt_fb(float* __restrict__ dis, int N)
{
    int n = blockIdx.x * 256 + threadIdx.x;
    if (n < N) dis[n] = rsqrtf(dis[n]);
}

// K3: symmetric degree normalization, gathers precomputed dis.
__global__ __launch_bounds__(256) void k3_edge2(
    const int* __restrict__ row, const int* __restrict__ col,
    float* __restrict__ out, const float* __restrict__ dis, int E)
{
    int e = blockIdx.x * 256 + threadIdx.x;
    if (e >= E) return;
    out[e] = out[e] * dis[row[e]] * dis[col[e]];
}

extern "C" void kernel_launch(void* const* d_in, const int* in_sizes, int n_in,
                              void* d_out, int out_size, void* d_ws, size_t ws_size,
                              hipStream_t stream) {
    const float* x      = (const float*)d_in[0];
    const float* W_nb   = (const float*)d_in[1];
    const float* b_nb   = (const float*)d_in[2];
    const float* W_self = (const float*)d_in[3];
    const float* b_self = (const float*)d_in[4];
    const float* W_att  = (const float*)d_in[5];
    const float* b_att  = (const float*)d_in[6];
    const float* values = (const float*)d_in[7];
    const float* noise  = (const float*)d_in[8];
    const int*   row    = (const int*)d_in[9];
    const int*   col    = (const int*)d_in[10];

    const int N = in_sizes[0] / D_DIM;
    const int E = in_sizes[7];
    float* out = (float*)d_out;

    char* ws = (char*)d_ws;
    ushort* Wt     = (ushort*)ws;                       // 131072 B
    float*  g_nb   = (float*)(ws + 131072);             // N
    float*  g_self = g_nb + N;                          // N
    float*  dis    = g_self + N;                        // N
    float*  priv   = dis + N;                           // S * Npad

    const int RS   = (N + 1) / 2;                       // rows per half-range
    const int Npad = 2 * RS;
    size_t base_bytes = 131072 + (size_t)3 * N * 4;

    // pick slice count S (pow2) fitting ws and giving ES >= 1
    int S = 128;
    while (S > 1 && base_bytes + (size_t)S * Npad * 4 > ws_size) S >>= 1;
    bool lds_path = (RS <= MAX_RS) && (base_bytes + (size_t)S * Npad * 4 <= ws_size) && (S >= 2);

    k0_init<<<( (2*H_DIM*D_DIM > N ? 2*H_DIM*D_DIM : N) + 255) / 256, 256, 0, stream>>>(
        W_nb, W_self, Wt, dis, N, lds_path ? 0 : 1);

    k1_gemm<<<(N + 63) / 64, 128, 0, stream>>>(x, Wt, b_nb, b_self, W_att, g_nb, g_self, N);

    int eb4 = ((E + 3) / 4 + 255) / 256;
    k2a_gate<<<eb4, 256, 0, stream>>>(row, col, values, noise, g_nb, g_self, b_att, out, E);

    int eb1 = (E + 255) / 256;
    if (lds_path) {
        int ES = (E + S - 1) / S;
        k2b_scatter<<<S * 2, 512, 0, stream>>>(row, out, priv, E, ES, RS, Npad);
        k2c_reduce<<<(N + 255) / 256, 256, 0, stream>>>(priv, dis, N, Npad, S);
    } else {
        k2b_atomic_fb<<<eb1, 256, 0, stream>>>(row, out, dis, E);
        k2c_rsqrt_fb<<<(N + 255) / 256, 256, 0, stream>>>(dis, N);
    }

    k3_edge2<<<eb1, 256, 0, stream>>>(row, col, out, dis, E);
}

// Round 6
// 79.958 us; speedup vs baseline: 1.3610x; 1.3610x over previous
//
#include <hip/hip_runtime.h>
#include <hip/hip_bf16.h>

typedef __attribute__((ext_vector_type(8))) short bf16x8;
typedef __attribute__((ext_vector_type(4))) float f32x4;

#define D_DIM 256   // input feature dim
#define H_DIM 128   // hidden dim per branch

// RNE float->bf16 (bit pattern)
__device__ inline ushort f2bf(float f) {
    union { float f; unsigned u; } a; a.f = f;
    unsigned r = a.u + 0x7fffu + ((a.u >> 16) & 1u);
    return (ushort)(r >> 16);
}

// K0: build Wt bf16 [hcat][k]; init dis buf to 1e-10 (fallback accumulator); zero priv.
__global__ void k0_init(const float* __restrict__ W_nb, const float* __restrict__ W_self,
                        ushort* __restrict__ Wt, float* __restrict__ dis,
                        float* __restrict__ priv, int N, int PN) {
    int i = blockIdx.x * 256 + threadIdx.x;
    if (i < 2 * H_DIM * D_DIM) {
        int sel = i >> 15;
        int r   = i & 32767;
        int k   = r >> 7;
        int h   = r & 127;
        const float* W = sel ? W_self : W_nb;
        Wt[(sel * H_DIM + h) * D_DIM + k] = f2bf(W[k * H_DIM + h]);
    }
    if (i < N) dis[i] = 1e-10f;
    if (i < PN) priv[i] = 0.f;
}

// K1: persistent-B fused GEMM.
//   grid = 256 blocks x 512 thr (8 waves). Wave w: rh = w>>2 (row half of 64-row tile),
//   cg = w&3 (64-col group; cg<2 -> nb branch, cg>=2 -> self branch).
//   B fragments for the wave's 64 cols x K=256 live in 128 VGPRs, loaded once.
//   Blocks grid-stride over 64-row tiles: stage A (f32->bf16) in LDS, MFMA, fused
//   bias+relu+W_att row-reduction; 2-way cross-wave combine in LDS.
__global__ __launch_bounds__(512, 2) void k1_gemm(
    const float* __restrict__ x, const ushort* __restrict__ Wt,
    const float* __restrict__ b_nb, const float* __restrict__ b_self,
    const float* __restrict__ W_att,
    float* __restrict__ g_nb, float* __restrict__ g_self, int N, int ntiles)
{
    __shared__ __align__(16) ushort A_lds[64][264];   // +8 pad: 2-way-conflict-free
    __shared__ float part[2][2][64];                  // [branch][colhalf][row]

    const int t    = threadIdx.x;
    const int lane = t & 63;
    const int w    = t >> 6;        // 0..7
    const int rh   = w >> 2;        // 0..1  (row half)
    const int cg   = w & 3;         // 0..3  (col group)
    const int br   = cg >> 1;       // 0: nb, 1: self
    const int ch   = cg & 1;        // col half within branch
    const int li   = lane & 15;
    const int grp  = lane >> 4;

    // ---- per-wave constants: bias + attention weight for my 4 ni cols ----
    float bias[4], aw[4];
    #pragma unroll
    for (int ni = 0; ni < 4; ni++) {
        int hh = ch * 64 + ni * 16 + li;               // 0..127 within branch
        bias[ni] = br ? b_self[hh] : b_nb[hh];
        aw[ni]   = W_att[br * H_DIM + hh];
    }

    // ---- persistent B fragments: 4 ni x 8 kslices x bf16x8 = 128 VGPR ----
    bf16x8 Bf[4][8];
    #pragma unroll
    for (int ni = 0; ni < 4; ni++)
        #pragma unroll
        for (int ks = 0; ks < 8; ks++)
            Bf[ni][ks] = *reinterpret_cast<const bf16x8*>(
                Wt + (size_t)(cg * 64 + ni * 16 + li) * D_DIM + ks * 32 + grp * 8);

    // staging coords: 8 threads/row, 8 float4 each
    const int sr = t >> 3;          // 0..63
    const int sc = t & 7;

    for (int rt = blockIdx.x; rt < ntiles; rt += gridDim.x) {
        const int row0 = rt * 64;

        __syncthreads();   // A_lds + part free for reuse
        // ---- stage A: 64 rows x 256 f32 -> bf16 LDS ----
        {
            const int gr = row0 + sr;
            const bool v = gr < N;
            const float4* src = reinterpret_cast<const float4*>(x + (size_t)gr * D_DIM);
            #pragma unroll
            for (int j = 0; j < 8; j++) {
                int c4 = sc + j * 8;
                ushort4 o;
                if (v) {
                    float4 f = src[c4];
                    o.x = f2bf(f.x); o.y = f2bf(f.y); o.z = f2bf(f.z); o.w = f2bf(f.w);
                } else { o.x = 0; o.y = 0; o.z = 0; o.w = 0; }
                *reinterpret_cast<ushort4*>(&A_lds[sr][c4 * 4]) = o;
            }
        }
        __syncthreads();

        // ---- MFMA over full K=256 ----
        f32x4 acc[2][4];
        #pragma unroll
        for (int mi = 0; mi < 2; mi++)
            #pragma unroll
            for (int ni = 0; ni < 4; ni++) acc[mi][ni] = f32x4{0.f, 0.f, 0.f, 0.f};

        #pragma unroll
        for (int ks = 0; ks < 8; ks++) {
            bf16x8 af0 = *reinterpret_cast<const bf16x8*>(&A_lds[rh * 32 + li][ks * 32 + grp * 8]);
            bf16x8 af1 = *reinterpret_cast<const bf16x8*>(&A_lds[rh * 32 + 16 + li][ks * 32 + grp * 8]);
            #pragma unroll
            for (int ni = 0; ni < 4; ni++) {
                acc[0][ni] = __builtin_amdgcn_mfma_f32_16x16x32_bf16(af0, Bf[ni][ks], acc[0][ni], 0, 0, 0);
                acc[1][ni] = __builtin_amdgcn_mfma_f32_16x16x32_bf16(af1, Bf[ni][ks], acc[1][ni], 0, 0, 0);
            }
        }

        // ---- epilogue: bias + relu + weighted col-sum, reduce over li ----
        float p[2][4];
        #pragma unroll
        for (int mi = 0; mi < 2; mi++)
            #pragma unroll
            for (int r4 = 0; r4 < 4; r4++) p[mi][r4] = 0.f;
        #pragma unroll
        for (int ni = 0; ni < 4; ni++)
            #pragma unroll
            for (int mi = 0; mi < 2; mi++)
                #pragma unroll
                for (int r4 = 0; r4 < 4; r4++) {
                    float y = acc[mi][ni][r4] + bias[ni];
                    y = y > 0.f ? y : 0.f;
                    p[mi][r4] += y * aw[ni];
                }
        #pragma unroll
        for (int mi = 0; mi < 2; mi++)
            #pragma unroll
            for (int r4 = 0; r4 < 4; r4++) {
                float v = p[mi][r4];
                #pragma unroll
                for (int m = 1; m < 16; m <<= 1) v += __shfl_xor(v, m);
                if (li == 0)
                    part[br][ch][rh * 32 + mi * 16 + grp * 4 + r4] = v;
            }
        __syncthreads();

        if (t < 128) {
            int b_ = t >> 6, lr = t & 63;
            int gr = row0 + lr;
            if (gr < N) {
                float val = part[b_][0][lr] + part[b_][1][lr];
                if (b_) g_self[gr] = val; else g_nb[gr] = val;
            }
        }
    }
}

// K2: edge pass 1 — 1 edge/thread. gate, mask, mv -> out; skip-zero atomic into priv.
// sigmoid(log(u/(1-u)) + la) = u / (u + (1-u)*exp(-la))
__global__ __launch_bounds__(256) void k2_edge1(
    const int* __restrict__ row, const int* __restrict__ col,
    const float* __restrict__ values, const float* __restrict__ noise,
    const float* __restrict__ g_nb, const float* __restrict__ g_self,
    const float* __restrict__ b_att,
    float* __restrict__ mv_out, float* __restrict__ priv,
    float* __restrict__ dis, int N, int P, int E)
{
    int e = blockIdx.x * 256 + threadIdx.x;
    if (e >= E) return;
    int   r = row[e], c = col[e];
    float v = values[e];
    float u = noise[e] + 1e-7f;
    float la = g_nb[r] + g_self[c] + b_att[0];
    float gate = u / (u + (1.f - u) * __expf(-la));
    float mask = fminf(fmaxf(gate * 1.6f - 0.5f, 0.f), 1.f);
    float m = v * mask;
    mv_out[e] = m;
    if (m != 0.f) {
        float* dst = (P > 0) ? (priv + (size_t)(blockIdx.x & (P - 1)) * N + r)
                             : (dis + r);
        atomicAdd(dst, m);
    }
}

// K2b: fold partials -> dis[n] = rsqrt(1e-10 + sum_p priv[p][n])
__global__ __launch_bounds__(256) void k2b_reduce(
    const float* __restrict__ priv, float* __restrict__ dis, int N, int P)
{
    int n = blockIdx.x * 256 + threadIdx.x;
    if (n >= N) return;
    float s = 1e-10f;
    for (int p = 0; p < P; p++) s += priv[(size_t)p * N + n];
    dis[n] = rsqrtf(s);
}

// Fallback finalize when P==0 (dis held raw sums)
__global__ __launch_bounds__(256) void k2c_rsqrt_fb(float* __restrict__ dis, int N)
{
    int n = blockIdx.x * 256 + threadIdx.x;
    if (n < N) dis[n] = rsqrtf(dis[n]);
}

// K3: symmetric degree normalization, gathers precomputed dis.
__global__ __launch_bounds__(256) void k3_edge2(
    const int* __restrict__ row, const int* __restrict__ col,
    float* __restrict__ out, const float* __restrict__ dis, int E)
{
    int e = blockIdx.x * 256 + threadIdx.x;
    if (e >= E) return;
    out[e] = out[e] * dis[row[e]] * dis[col[e]];
}

extern "C" void kernel_launch(void* const* d_in, const int* in_sizes, int n_in,
                              void* d_out, int out_size, void* d_ws, size_t ws_size,
                              hipStream_t stream) {
    const float* x      = (const float*)d_in[0];
    const float* W_nb   = (const float*)d_in[1];
    const float* b_nb   = (const float*)d_in[2];
    const float* W_self = (const float*)d_in[3];
    const float* b_self = (const float*)d_in[4];
    const float* W_att  = (const float*)d_in[5];
    const float* b_att  = (const float*)d_in[6];
    const float* values = (const float*)d_in[7];
    const float* noise  = (const float*)d_in[8];
    const int*   row    = (const int*)d_in[9];
    const int*   col    = (const int*)d_in[10];

    const int N = in_sizes[0] / D_DIM;
    const int E = in_sizes[7];
    float* out = (float*)d_out;

    char* ws = (char*)d_ws;
    ushort* Wt     = (ushort*)ws;                       // 131072 B
    float*  g_nb   = (float*)(ws + 131072);             // N
    float*  g_self = g_nb + N;                          // N
    float*  dis    = g_self + N;                        // N
    float*  priv   = dis + N;                           // P*N

    // privatization factor P (pow2, <=16) fitting workspace
    size_t base_bytes = 131072 + (size_t)3 * N * 4;
    int P = 16;
    while (P >= 1 && base_bytes + (size_t)P * N * 4 > ws_size) P >>= 1;
    if (P < 1) P = 0;
    const int PN = P * N;

    int init_n = 2 * H_DIM * D_DIM;
    if (N > init_n) init_n = N;
    if (PN > init_n) init_n = PN;
    k0_init<<<(init_n + 255) / 256, 256, 0, stream>>>(W_nb, W_self, Wt, dis, priv, N, PN);

    const int ntiles = (N + 63) / 64;
    k1_gemm<<<256, 512, 0, stream>>>(x, Wt, b_nb, b_self, W_att, g_nb, g_self, N, ntiles);

    int eb1 = (E + 255) / 256;
    k2_edge1<<<eb1, 256, 0, stream>>>(row, col, values, noise, g_nb, g_self, b_att,
                                      out, priv, dis, N, P, E);
    if (P > 0)
        k2b_reduce<<<(N + 255) / 256, 256, 0, stream>>>(priv, dis, N, P);
    else
        k2c_rsqrt_fb<<<(N + 255) / 256, 256, 0, stream>>>(dis, N);

    k3_edge2<<<eb1, 256, 0, stream>>>(row, col, out, dis, E);
}